// Round 5
// baseline (83.535 us; speedup 1.0000x reference)
//
#include <hip/hip_runtime.h>
#include <cstddef>

#define BB 4
#define CC 64
#define NN 8192
#define KK 16
#define OO 128

#define SH 136   // LDS row stride (bf16 elems) for h tile: 272B rows, 2-way max bank alias

typedef __attribute__((ext_vector_type(8))) short bf16x8;
typedef __attribute__((ext_vector_type(4))) float f32x4;
typedef __attribute__((ext_vector_type(4))) int   i32x4;

__device__ __forceinline__ unsigned short f2b(float f) {
    unsigned u = __builtin_bit_cast(unsigned, f);
    unsigned r = (u + 0x7fffu + ((u >> 16) & 1u)) >> 16;   // RNE
    return (unsigned short)r;
}

__device__ __forceinline__ float bclo(unsigned d) {       // low bf16 -> f32
    return __builtin_bit_cast(float, d << 16);
}
__device__ __forceinline__ float bchi(unsigned d) {       // high bf16 -> f32
    return __builtin_bit_cast(float, d & 0xffff0000u);
}

// XCD-locality decode: under round-robin bid%8 XCD assignment, XCD pair {2b,2b+1}
// serves only batch b -> per-XCD gather working set 1 MB (L2-resident), not 4 MB.
__device__ __forceinline__ void decode_bid(int bid, int& b, int& tile) {
    int xcd = bid & 7;
    b    = xcd >> 1;                      // 0..3
    tile = ((bid >> 3) << 1) | (xcd & 1); // 0..127, bijective with b over 512 blocks
}

// x: (B, C, N) fp32 -> xt: (B, N, C) bf16.  Also 16 designated blocks: W fp32 -> Wbf bf16.
__global__ __launch_bounds__(256) void transpose_kernel(
        const float* __restrict__ x, unsigned short* __restrict__ xt,
        const float* __restrict__ W, unsigned short* __restrict__ Wbf) {
    __shared__ float tile_s[64][65];
    int b, tl;
    decode_bid(blockIdx.x, b, tl);
    const int n0 = tl * 64;
    const int t  = threadIdx.x;
    const int ln = t & 63;
    const int r  = t >> 6;

    const float* xb = x + (size_t)b * CC * NN;
    #pragma unroll
    for (int s = 0; s < 64; s += 4) {
        int c = s + r;
        tile_s[c][ln] = xb[(size_t)c * NN + n0 + ln];
    }
    __syncthreads();
    unsigned short* xtb = xt + ((size_t)b * NN + n0) * CC;
    // each thread packs 4 consecutive channels of one node -> 8B stores,
    // a wave covers 4 consecutive node rows = 512 contiguous bytes
    const int c4 = (t & 15) * 4;
    const int nn = t >> 4;               // 0..15
    #pragma unroll
    for (int s = 0; s < 64; s += 16) {
        int n = s + nn;
        ushort4 o;
        o.x = f2b(tile_s[c4 + 0][n]);
        o.y = f2b(tile_s[c4 + 1][n]);
        o.z = f2b(tile_s[c4 + 2][n]);
        o.w = f2b(tile_s[c4 + 3][n]);
        *reinterpret_cast<ushort4*>(xtb + n * CC + c4) = o;
    }

    if (b == 0 && tl < 16) {             // 16 unique blocks convert W (tl*1024 covers 16K elems)
        int idx = tl * 1024 + t * 4;
        float4 v = *reinterpret_cast<const float4*>(W + idx);
        ushort4 o;
        o.x = f2b(v.x); o.y = f2b(v.y); o.z = f2b(v.z); o.w = f2b(v.w);
        *reinterpret_cast<ushort4*>(Wbf + idx) = o;
    }
}

// gather batch of 4 k's (static base KB) — all indices compile-time so arrays stay in regs
template<int KB>
__device__ __forceinline__ void loadb(uint4* XJ, uint4* XI, const unsigned short* xtb,
                                      const int* ejp, const int* eip, int p) {
    #pragma unroll
    for (int q = 0; q < 4; q++) {
        XJ[q] = *reinterpret_cast<const uint4*>(xtb + (size_t)ejp[KB + q] * CC + p * 8);
        XI[q] = *reinterpret_cast<const uint4*>(xtb + (size_t)eip[KB + q] * CC + p * 8);
    }
}

__device__ __forceinline__ void consume(const uint4* XJ, const uint4* XI, float* m) {
    #pragma unroll
    for (int q = 0; q < 4; q++) {
        m[0] = fmaxf(m[0], bclo(XJ[q].x) - bclo(XI[q].x));
        m[1] = fmaxf(m[1], bchi(XJ[q].x) - bchi(XI[q].x));
        m[2] = fmaxf(m[2], bclo(XJ[q].y) - bclo(XI[q].y));
        m[3] = fmaxf(m[3], bchi(XJ[q].y) - bchi(XI[q].y));
        m[4] = fmaxf(m[4], bclo(XJ[q].z) - bclo(XI[q].z));
        m[5] = fmaxf(m[5], bchi(XJ[q].z) - bchi(XI[q].z));
        m[6] = fmaxf(m[6], bclo(XJ[q].w) - bclo(XI[q].w));
        m[7] = fmaxf(m[7], bchi(XJ[q].w) - bchi(XI[q].w));
    }
}

// xt: (B,N,64) bf16; Wbf: (128,128) bf16; eidx: (2,B,N,16); bias: (128); out: (B,128,N) fp32
__global__ __launch_bounds__(512, 4) void main_kernel(
        const unsigned short* __restrict__ xt,
        const unsigned short* __restrict__ Wbf,
        const int*            __restrict__ eidx,
        const float*          __restrict__ bias,
        float*                __restrict__ out) {
    __shared__ unsigned short hl[64 * SH];    // 17408 B
    __shared__ int eL[2048];                  // [0..1023]=e0 slab, [1024..2047]=e1 slab

    const int t    = threadIdx.x;
    const int lane = t & 63;
    const int w    = t >> 6;                  // 0..7
    int b, tl;
    decode_bid(blockIdx.x, b, tl);
    const int n_base = tl * 64;

    const int quad = lane >> 4;
    const int l15  = lane & 15;
    const int o0   = w * 16;                  // 8 waves x 16 output rows = 128

    // ---- stage indices (coalesced, nontemporal: streamed once, keep L2 for xt) ----
    const int* e0 = eidx + ((size_t)b * NN + n_base) * KK;
    const int* e1 = e0 + (size_t)BB * NN * KK;
    if (t < 256) {
        i32x4 v = __builtin_nontemporal_load(
            reinterpret_cast<const i32x4*>(e0 + t * 4));
        *reinterpret_cast<i32x4*>(&eL[t * 4]) = v;
    } else {
        int u = t - 256;
        i32x4 v = __builtin_nontemporal_load(
            reinterpret_cast<const i32x4*>(e1 + u * 4));
        *reinterpret_cast<i32x4*>(&eL[1024 + u * 4]) = v;
    }

    // own-row load is index-independent: issue before the barrier
    const unsigned short* xtb = xt + (size_t)b * NN * CC;
    const int nl = t >> 3;       // node within tile, 0..63
    const int p  = t & 7;        // 16B chunk within row (channels p*8 .. p*8+7)
    uint4 xr = *reinterpret_cast<const uint4*>(xtb + (size_t)(n_base + nl) * CC + p * 8);

    __syncthreads();

    // ---- phase 1: gather + max, double-buffered 8-load batches for deep MLP ----
    const int* ejp = &eL[nl * KK];            // e0 slab -> x_j
    const int* eip = &eL[1024 + nl * KK];     // e1 slab -> x_i

    float m[8];
    #pragma unroll
    for (int j = 0; j < 8; j++) m[j] = -1e30f;

    uint4 xjA[4], xiA[4], xjB[4], xiB[4];
    loadb<0>(xjA, xiA, xtb, ejp, eip, p);     // 8 loads in flight
    loadb<4>(xjB, xiB, xtb, ejp, eip, p);     // 16 in flight
    consume(xjA, xiA, m);                     // waits first 8 only
    loadb<8>(xjA, xiA, xtb, ejp, eip, p);
    consume(xjB, xiB, m);
    loadb<12>(xjB, xiB, xtb, ejp, eip, p);
    consume(xjA, xiA, m);
    consume(xjB, xiB, m);

    // ---- W fragments + bias: needed only in phase 2; issue now so the L2
    //      latency hides under pack + barrier (kept out of phase 1's VGPR budget) ----
    bf16x8 afr[4];
    #pragma unroll
    for (int ks = 0; ks < 4; ks++)
        afr[ks] = *reinterpret_cast<const bf16x8*>(
            Wbf + (o0 + l15) * 128 + ks * 32 + quad * 8);
    f32x4 bv = *reinterpret_cast<const f32x4*>(bias + o0 + quad * 4);

    // pack h[nl][2c]=x[c], h[nl][2c+1]=m[c] for c = p*8 .. p*8+7  (32B per lane)
    unsigned xs[8];
    xs[0] = xr.x & 0xffffu; xs[1] = xr.x >> 16;
    xs[2] = xr.y & 0xffffu; xs[3] = xr.y >> 16;
    xs[4] = xr.z & 0xffffu; xs[5] = xr.z >> 16;
    xs[6] = xr.w & 0xffffu; xs[7] = xr.w >> 16;
    unsigned od[8];
    #pragma unroll
    for (int j = 0; j < 8; j++)
        od[j] = xs[j] | ((unsigned)f2b(m[j]) << 16);

    {
        unsigned short* dst = &hl[nl * SH + p * 16];
        uint4 lo, hi;
        lo.x = od[0]; lo.y = od[1]; lo.z = od[2]; lo.w = od[3];
        hi.x = od[4]; hi.y = od[5]; hi.z = od[6]; hi.w = od[7];
        *reinterpret_cast<uint4*>(dst)     = lo;
        *reinterpret_cast<uint4*>(dst + 8) = hi;
    }
    __syncthreads();

    // ---- phase 2: out[128 x 64] = W[128x128] @ h[128x64], MFMA bf16 ----
    #pragma unroll
    for (int nt = 0; nt < 4; nt++) {
        f32x4 acc = {0.f, 0.f, 0.f, 0.f};
        #pragma unroll
        for (int ks = 0; ks < 4; ks++) {
            const unsigned short* bp = &hl[(nt * 16 + l15) * SH + ks * 32 + quad * 8];
            bf16x8 bfr = *reinterpret_cast<const bf16x8*>(bp);
            acc = __builtin_amdgcn_mfma_f32_16x16x32_bf16(afr[ks], bfr, acc, 0, 0, 0);
        }
        int n_g = n_base + nt * 16 + l15;
        #pragma unroll
        for (int r = 0; r < 4; r++) {
            int o = o0 + quad * 4 + r;
            float v = fmaxf(acc[r] + bv[r], 0.f);
            // out is written once, never read: nontemporal keeps xt resident in L2
            __builtin_nontemporal_store(v, &out[((size_t)b * OO + o) * NN + n_g]);
        }
    }
}

extern "C" void kernel_launch(void* const* d_in, const int* in_sizes, int n_in,
                              void* d_out, int out_size, void* d_ws, size_t ws_size,
                              hipStream_t stream) {
    const float* x    = (const float*)d_in[0];
    const int*   eidx = (const int*)d_in[1];
    const float* W    = (const float*)d_in[2];
    const float* bias = (const float*)d_in[3];
    float* out = (float*)d_out;

    unsigned short* xt  = (unsigned short*)d_ws;                            // 4 MB
    unsigned short* Wbf = (unsigned short*)((char*)d_ws + 4 * 1024 * 1024); // 32 KB

    transpose_kernel<<<dim3(NN / 64 * BB), dim3(256), 0, stream>>>(x, xt, W, Wbf);
    main_kernel<<<dim3(NN / 64 * BB), dim3(512), 0, stream>>>(xt, Wbf, eidx, bias, out);
}

// Round 6
// 80.799 us; speedup vs baseline: 1.0339x; 1.0339x over previous
//
#include <hip/hip_runtime.h>
#include <cstddef>

#define BB 4
#define CC 64
#define NN 8192
#define KK 16
#define OO 128

#define SH 136   // LDS row stride (bf16 elems) for h tile: 272B rows, 2-way max bank alias

typedef __attribute__((ext_vector_type(8))) short bf16x8;
typedef __attribute__((ext_vector_type(4))) float f32x4;
typedef __attribute__((ext_vector_type(4))) int   i32x4;

__device__ __forceinline__ unsigned short f2b(float f) {
    unsigned u = __builtin_bit_cast(unsigned, f);
    unsigned r = (u + 0x7fffu + ((u >> 16) & 1u)) >> 16;   // RNE
    return (unsigned short)r;
}

__device__ __forceinline__ float bclo(unsigned d) {       // low bf16 -> f32
    return __builtin_bit_cast(float, d << 16);
}
__device__ __forceinline__ float bchi(unsigned d) {       // high bf16 -> f32
    return __builtin_bit_cast(float, d & 0xffff0000u);
}

// x: (B, C, N) fp32 -> xt: (B, N, C) bf16.  Also (16 blocks of y==0) W fp32 -> Wbf bf16.
__global__ __launch_bounds__(256) void transpose_kernel(
        const float* __restrict__ x, unsigned short* __restrict__ xt,
        const float* __restrict__ W, unsigned short* __restrict__ Wbf) {
    __shared__ float tile[64][65];
    const int b  = blockIdx.y;
    const int n0 = blockIdx.x * 64;
    const int t  = threadIdx.x;
    const int ln = t & 63;
    const int r  = t >> 6;

    const float* xb = x + (size_t)b * CC * NN;
    #pragma unroll
    for (int s = 0; s < 64; s += 4) {
        int c = s + r;
        tile[c][ln] = xb[(size_t)c * NN + n0 + ln];
    }
    __syncthreads();
    unsigned short* xtb = xt + ((size_t)b * NN + n0) * CC;
    // each thread packs 4 consecutive channels of one node -> 8B stores,
    // a wave covers 4 consecutive node rows = 512 contiguous bytes
    const int c4 = (t & 15) * 4;
    const int nn = t >> 4;               // 0..15
    #pragma unroll
    for (int s = 0; s < 64; s += 16) {
        int n = s + nn;
        ushort4 o;
        o.x = f2b(tile[c4 + 0][n]);
        o.y = f2b(tile[c4 + 1][n]);
        o.z = f2b(tile[c4 + 2][n]);
        o.w = f2b(tile[c4 + 3][n]);
        *reinterpret_cast<ushort4*>(xtb + n * CC + c4) = o;
    }

    if (b == 0 && blockIdx.x < 16) {
        int idx = blockIdx.x * 1024 + t * 4;
        float4 v = *reinterpret_cast<const float4*>(W + idx);
        ushort4 o;
        o.x = f2b(v.x); o.y = f2b(v.y); o.z = f2b(v.z); o.w = f2b(v.w);
        *reinterpret_cast<ushort4*>(Wbf + idx) = o;
    }
}

// gather batch of 4 k's (static base KB) — all indices compile-time so arrays stay in regs
template<int KB>
__device__ __forceinline__ void loadb(uint4* XJ, uint4* XI, const unsigned short* xtb,
                                      const int* ejp, const int* eip, int p) {
    #pragma unroll
    for (int q = 0; q < 4; q++) {
        XJ[q] = *reinterpret_cast<const uint4*>(xtb + (size_t)ejp[KB + q] * CC + p * 8);
        XI[q] = *reinterpret_cast<const uint4*>(xtb + (size_t)eip[KB + q] * CC + p * 8);
    }
}

__device__ __forceinline__ void consume(const uint4* XJ, const uint4* XI, float* m) {
    #pragma unroll
    for (int q = 0; q < 4; q++) {
        m[0] = fmaxf(m[0], bclo(XJ[q].x) - bclo(XI[q].x));
        m[1] = fmaxf(m[1], bchi(XJ[q].x) - bchi(XI[q].x));
        m[2] = fmaxf(m[2], bclo(XJ[q].y) - bclo(XI[q].y));
        m[3] = fmaxf(m[3], bchi(XJ[q].y) - bchi(XI[q].y));
        m[4] = fmaxf(m[4], bclo(XJ[q].z) - bclo(XI[q].z));
        m[5] = fmaxf(m[5], bchi(XJ[q].z) - bchi(XI[q].z));
        m[6] = fmaxf(m[6], bclo(XJ[q].w) - bclo(XI[q].w));
        m[7] = fmaxf(m[7], bchi(XJ[q].w) - bchi(XI[q].w));
    }
}

// xt: (B,N,64) bf16; Wbf: (128,128) bf16; eidx: (2,B,N,16); bias: (128); out: (B,128,N) fp32
__global__ __launch_bounds__(512, 4) void main_kernel(
        const unsigned short* __restrict__ xt,
        const unsigned short* __restrict__ Wbf,
        const int*            __restrict__ eidx,
        const float*          __restrict__ bias,
        float*                __restrict__ out) {
    __shared__ unsigned short hl[64 * SH];    // 17408 B
    __shared__ int eL[2048];                  // [0..1023]=e0 slab, [1024..2047]=e1 slab

    const int t    = threadIdx.x;
    const int lane = t & 63;
    const int w    = t >> 6;                  // 0..7
    const int b    = blockIdx.y;
    const int n_base = blockIdx.x * 64;

    const int quad = lane >> 4;
    const int l15  = lane & 15;
    const int o0   = w * 16;                  // 8 waves x 16 output rows = 128

    // ---- stage indices (coalesced, nontemporal: streamed once, keep L2 for xt) ----
    const int* e0 = eidx + ((size_t)b * NN + n_base) * KK;
    const int* e1 = e0 + (size_t)BB * NN * KK;
    if (t < 256) {
        i32x4 v = __builtin_nontemporal_load(
            reinterpret_cast<const i32x4*>(e0 + t * 4));
        *reinterpret_cast<i32x4*>(&eL[t * 4]) = v;
    } else {
        int u = t - 256;
        i32x4 v = __builtin_nontemporal_load(
            reinterpret_cast<const i32x4*>(e1 + u * 4));
        *reinterpret_cast<i32x4*>(&eL[1024 + u * 4]) = v;
    }

    // own-row load is index-independent: issue before the barrier
    const unsigned short* xtb = xt + (size_t)b * NN * CC;
    const int nl = t >> 3;       // node within tile, 0..63
    const int p  = t & 7;        // 16B chunk within row (channels p*8 .. p*8+7)
    uint4 xr = *reinterpret_cast<const uint4*>(xtb + (size_t)(n_base + nl) * CC + p * 8);

    __syncthreads();

    // ---- phase 1: gather + max, double-buffered 8-load batches for deep MLP ----
    const int* ejp = &eL[nl * KK];            // e0 slab -> x_j
    const int* eip = &eL[1024 + nl * KK];     // e1 slab -> x_i

    float m[8];
    #pragma unroll
    for (int j = 0; j < 8; j++) m[j] = -1e30f;

    uint4 xjA[4], xiA[4], xjB[4], xiB[4];
    loadb<0>(xjA, xiA, xtb, ejp, eip, p);     // 8 loads in flight
    loadb<4>(xjB, xiB, xtb, ejp, eip, p);     // 16 in flight
    consume(xjA, xiA, m);                     // waits first 8 only
    loadb<8>(xjA, xiA, xtb, ejp, eip, p);
    consume(xjB, xiB, m);
    loadb<12>(xjB, xiB, xtb, ejp, eip, p);
    consume(xjA, xiA, m);
    consume(xjB, xiB, m);

    // ---- W fragments + bias: needed only in phase 2; issue now so the L2
    //      latency hides under pack + barrier (kept out of phase 1's VGPR budget) ----
    bf16x8 afr[4];
    #pragma unroll
    for (int ks = 0; ks < 4; ks++)
        afr[ks] = *reinterpret_cast<const bf16x8*>(
            Wbf + (o0 + l15) * 128 + ks * 32 + quad * 8);
    f32x4 bv = *reinterpret_cast<const f32x4*>(bias + o0 + quad * 4);

    // pack h[nl][2c]=x[c], h[nl][2c+1]=m[c] for c = p*8 .. p*8+7  (32B per lane)
    unsigned xs[8];
    xs[0] = xr.x & 0xffffu; xs[1] = xr.x >> 16;
    xs[2] = xr.y & 0xffffu; xs[3] = xr.y >> 16;
    xs[4] = xr.z & 0xffffu; xs[5] = xr.z >> 16;
    xs[6] = xr.w & 0xffffu; xs[7] = xr.w >> 16;
    unsigned od[8];
    #pragma unroll
    for (int j = 0; j < 8; j++)
        od[j] = xs[j] | ((unsigned)f2b(m[j]) << 16);

    {
        unsigned short* dst = &hl[nl * SH + p * 16];
        uint4 lo, hi;
        lo.x = od[0]; lo.y = od[1]; lo.z = od[2]; lo.w = od[3];
        hi.x = od[4]; hi.y = od[5]; hi.z = od[6]; hi.w = od[7];
        *reinterpret_cast<uint4*>(dst)     = lo;
        *reinterpret_cast<uint4*>(dst + 8) = hi;
    }
    __syncthreads();

    // ---- phase 2: out[128 x 64] = W[128x128] @ h[128x64], MFMA bf16 ----
    #pragma unroll
    for (int nt = 0; nt < 4; nt++) {
        f32x4 acc = {0.f, 0.f, 0.f, 0.f};
        #pragma unroll
        for (int ks = 0; ks < 4; ks++) {
            const unsigned short* bp = &hl[(nt * 16 + l15) * SH + ks * 32 + quad * 8];
            bf16x8 bfr = *reinterpret_cast<const bf16x8*>(bp);
            acc = __builtin_amdgcn_mfma_f32_16x16x32_bf16(afr[ks], bfr, acc, 0, 0, 0);
        }
        int n_g = n_base + nt * 16 + l15;
        #pragma unroll
        for (int r = 0; r < 4; r++) {
            int o = o0 + quad * 4 + r;
            float v = fmaxf(acc[r] + bv[r], 0.f);
            // out is written once, never read: nontemporal keeps xt resident in L2
            __builtin_nontemporal_store(v, &out[((size_t)b * OO + o) * NN + n_g]);
        }
    }
}

extern "C" void kernel_launch(void* const* d_in, const int* in_sizes, int n_in,
                              void* d_out, int out_size, void* d_ws, size_t ws_size,
                              hipStream_t stream) {
    const float* x    = (const float*)d_in[0];
    const int*   eidx = (const int*)d_in[1];
    const float* W    = (const float*)d_in[2];
    const float* bias = (const float*)d_in[3];
    float* out = (float*)d_out;

    unsigned short* xt  = (unsigned short*)d_ws;                            // 4 MB
    unsigned short* Wbf = (unsigned short*)((char*)d_ws + 4 * 1024 * 1024); // 32 KB

    transpose_kernel<<<dim3(NN / 64, BB), dim3(256), 0, stream>>>(x, xt, W, Wbf);
    main_kernel<<<dim3(NN / 64, BB), dim3(512), 0, stream>>>(xt, Wbf, eidx, bias, out);
}